// Round 12
// baseline (394.377 us; speedup 1.0000x reference)
//
#include <hip/hip_runtime.h>
#include <hip/hip_bf16.h>
#include <cstdint>

// Problem constants
#define BB 4
#define TT 2048
#define EE 1024
#define HH 16
#define DD 64
#define BH (BB*HH)       // 64
#define MM (BB*TT)       // 8192 rows for projection GEMMs
#define KK 1024          // contraction dim for projections
#define KSTR 72          // flash K-tile LDS row stride (ushorts)
#define VSTR 136         // flash V-tile LDS row stride (ushorts)
#define LOG2E 1.44269504088896340736f

typedef __attribute__((ext_vector_type(8))) short short8;    // 8 x bf16
typedef __attribute__((ext_vector_type(4))) short short4_;   // 4 x bf16
typedef __attribute__((ext_vector_type(4))) float float4_;   // MFMA accumulator
typedef __attribute__((ext_vector_type(4))) ushort ushort4_;

__device__ __forceinline__ void gl_lds16(const void* g, void* l) {
    __builtin_amdgcn_global_load_lds(
        (const __attribute__((address_space(1))) void*)g,
        (__attribute__((address_space(3))) void*)l, 16, 0, 0);
}

__device__ __forceinline__ ushort f2bf(float v) {
    __hip_bfloat16 h = __float2bfloat16(v);
    return *(ushort*)&h;
}

// ---------------------------------------------------------------------------
// fp32 -> bf16 conversion (weights only). grid.y selects segment.
// ---------------------------------------------------------------------------
__global__ __launch_bounds__(256) void cvt_kernel(
    const float* __restrict__ s0, ushort* __restrict__ d0, int n0,
    const float* __restrict__ s1, ushort* __restrict__ d1, int n1,
    const float* __restrict__ s2, ushort* __restrict__ d2, int n2,
    const float* __restrict__ s3, ushort* __restrict__ d3, int n3)
{
    const float* s; ushort* d; int n;
    switch (blockIdx.y) {
        case 0: s = s0; d = d0; n = n0; break;
        case 1: s = s1; d = d1; n = n1; break;
        case 2: s = s2; d = d2; n = n2; break;
        default: s = s3; d = d3; n = n3; break;
    }
    int i = (blockIdx.x * 256 + threadIdx.x) * 4;
    if (i >= n) return;
    float4_ v = *(const float4_*)&s[i];
    ushort4_ o;
#pragma unroll
    for (int j = 0; j < 4; j++) o[j] = f2bf(v[j]);
    *(ushort4_*)&d[i] = o;
}

// ---------------------------------------------------------------------------
// MERGED Q/K/V projection GEMM.  1D grid + XCD-chunked bijective swizzle.
//
// Round-12 change: T3 MINIMUM 2-PHASE PIPELINE.  R11 showed the swizzle cut
// bank conflicts 2.2e7->9.4e6 but time only -3% -> the critical path is the
// stage+drain+barrier structure (m252/m233): __syncthreads() drains vmcnt(0)
// on the loads JUST issued, exposing full L2 latency every k-step.  Now:
// double-buffered LDS tiles; STAGE(t+1) issued BEFORE computing tile t;
// inline-asm s_waitcnt vmcnt(0) + RAW s_barrier placed AFTER the MFMAs.
// The stage latency elapses under ds_read+MFMA; the drain finds loads done.
// Ordering: buf[cur] reads were staged at t-1, drained by t-1's vmcnt+bar;
// buf[cur^1] (overwritten at t) was last read at t-1 and every wave's reads
// complete before it passes the t-1 barrier.
// LDS 48 KB (2 x (16K fp32 A + 8K bf16 W)) -> 3 blocks/CU.
// A-tile XOR-swizzle (R11) and XCD swizzle (R9) retained.
// C[n,e] = (sum_k A[n,k]*W[e,k] + bias[e])*scale
// z=0,1: scatter bf16 per-head [B*H, T, D];  z=2: transposed [B*H, D, T].
// ---------------------------------------------------------------------------
__global__ __launch_bounds__(256, 3) void gemm_qkv(
    const float* __restrict__ Aq, const float* __restrict__ Ak,
    const float* __restrict__ Av,
    const ushort* __restrict__ Wqc, const ushort* __restrict__ Wkc,
    const ushort* __restrict__ Wvc,
    const float* __restrict__ bq, const float* __restrict__ bk,
    const float* __restrict__ bv,
    ushort* __restrict__ Oq, ushort* __restrict__ Ok, ushort* __restrict__ Ov,
    float qscale)
{
    __shared__ __align__(16) float  Asf[2][128*32];   // 2 x 16 KB (swizzled)
    __shared__ __align__(16) ushort Bs [2][128*32];   // 2 x  8 KB

    const int bid = blockIdx.x;
    const int swz = (bid & 7) * 192 + (bid >> 3);
    const int z   = swz >> 9;          // 512 blocks per z
    const int rem = swz & 511;
    const int bx  = rem & 7;           // col-block (x fastest within chunk)
    const int by  = rem >> 3;          // row-block

    const float*  A    = (z == 0) ? Aq  : (z == 1) ? Ak  : Av;
    const ushort* W    = (z == 0) ? Wqc : (z == 1) ? Wkc : Wvc;
    const float*  bias = (z == 0) ? bq  : (z == 1) ? bk  : bv;
    ushort*       Cout = (z == 0) ? Oq  : (z == 1) ? Ok  : Ov;
    const float   scale = (z == 0) ? qscale : 1.0f;
    const bool    modeT = (z == 2);

    const int tid  = threadIdx.x;
    const int wave = tid >> 6;
    const int lane = tid & 63;
    const int l15  = lane & 15;
    const int quad = lane >> 4;
    const int wm   = wave & 1;   // row half
    const int wn   = wave >> 1;  // col half

    const long rowBase = (long)by * 128;
    const long colBase = (long)bx * 128;

    // stage one k-step's A (fp32, source-swizzled) + W (bf16) into buf
    auto STAGE = [&](int buf, int k0) {
#pragma unroll
        for (int it = 0; it < 4; it++) {
            int idx = it * 256 + tid;
            int r = idx >> 3, c = idx & 7;
            int csrc = c ^ (r & 7);
            gl_lds16(A + (rowBase + r) * KK + k0 + csrc * 4, &Asf[buf][idx * 4]);
        }
#pragma unroll
        for (int it = 0; it < 2; it++) {
            int idx = it * 256 + tid;
            int r = idx >> 2, c8 = (idx & 3) * 8;
            gl_lds16(W + (colBase + r) * KK + k0 + c8, &Bs[buf][idx * 8]);
        }
    };

    float4_ acc[4][4];
#pragma unroll
    for (int i = 0; i < 4; i++)
#pragma unroll
        for (int j = 0; j < 4; j++) acc[i][j] = float4_{0.f, 0.f, 0.f, 0.f};

    // prologue: stage tile 0, drain, publish
    STAGE(0, 0);
    asm volatile("s_waitcnt vmcnt(0)" ::: "memory");
    __builtin_amdgcn_s_barrier();

    const int NT = KK / 32;
    for (int t = 0; t < NT; t++) {
        const int cur = t & 1;
        // issue next tile's loads FIRST (latency hides under compute below)
        if (t + 1 < NT) STAGE(cur ^ 1, (t + 1) * 32);

        // fragments from buf[cur]: A fp32+cvt with XOR, W plain bf16
        short8 af[4], bf[4];
#pragma unroll
        for (int mt = 0; mt < 4; mt++) {
            const int r = wm*64 + mt*16 + l15;
            const int s = r & 7;
            const float* arow = &Asf[cur][r * 32];
            float4_ a0 = *(const float4_*)&arow[((2*quad    ) ^ s) * 4];
            float4_ a1 = *(const float4_*)&arow[((2*quad + 1) ^ s) * 4];
#pragma unroll
            for (int j = 0; j < 4; j++) {
                af[mt][j]     = (short)f2bf(a0[j]);
                af[mt][j + 4] = (short)f2bf(a1[j]);
            }
        }
#pragma unroll
        for (int nt = 0; nt < 4; nt++)
            bf[nt] = *(const short8*)&Bs[cur][(wn*64 + nt*16 + l15) * 32 + quad*8];
#pragma unroll
        for (int mt = 0; mt < 4; mt++)
#pragma unroll
            for (int nt = 0; nt < 4; nt++)
                acc[mt][nt] = __builtin_amdgcn_mfma_f32_16x16x32_bf16(
                    af[mt], bf[nt], acc[mt][nt], 0, 0, 0);

        // drain next tile's loads (mostly complete by now) and publish
        if (t + 1 < NT) {
            asm volatile("s_waitcnt vmcnt(0)" ::: "memory");
            __builtin_amdgcn_s_barrier();
        }
    }

    // Epilogue: C/D layout col = lane&15, row = quad*4 + reg
#pragma unroll
    for (int nt = 0; nt < 4; nt++) {
        const long col = colBase + wn*64 + nt*16 + l15;
        const float bvv = bias[col];
        const long h = col >> 6, d = col & (DD - 1);
#pragma unroll
        for (int mt = 0; mt < 4; mt++) {
            const long row0 = rowBase + wm*64 + mt*16 + quad*4;
            if (modeT) {
                const long b = row0 >> 11, t0 = row0 & (TT - 1);
                ushort4_ pk;
#pragma unroll
                for (int i = 0; i < 4; i++) pk[i] = f2bf((acc[mt][nt][i] + bvv) * scale);
                *(ushort4_*)&Cout[((b*HH + h)*DD + d)*TT + t0] = pk;
            } else {
#pragma unroll
                for (int i = 0; i < 4; i++) {
                    const long row = row0 + i;
                    const long b = row >> 11, t = row & (TT - 1);
                    Cout[(((b*HH + h) * TT) + t) * DD + d] =
                        f2bf((acc[mt][nt][i] + bvv) * scale);
                }
            }
        }
    }
}

// ---------------------------------------------------------------------------
// Output GEMM: same T3 2-phase pipeline (both operands bf16 via gl_lds),
// double-buffered 32 KB LDS, XCD swizzle.
// C fp32 row-major [MM, EE] = (AO @ Wo^T + bo)
// ---------------------------------------------------------------------------
__global__ __launch_bounds__(256, 3) void gemm_out(
    const ushort* __restrict__ A, const ushort* __restrict__ W,
    const float* __restrict__ bias, float* __restrict__ Cout)
{
    __shared__ __align__(16) ushort As[2][128*32];
    __shared__ __align__(16) ushort Bs[2][128*32];

    const int bid = blockIdx.x;
    const int swz = (bid & 7) * 64 + (bid >> 3);   // 512 blocks, 64/chunk
    const int bx  = swz & 7;
    const int by  = swz >> 3;

    const int tid  = threadIdx.x;
    const int wave = tid >> 6;
    const int lane = tid & 63;
    const int l15  = lane & 15;
    const int quad = lane >> 4;
    const int wm   = wave & 1;
    const int wn   = wave >> 1;

    const long rowBase = (long)by * 128;
    const long colBase = (long)bx * 128;

    auto STAGE = [&](int buf, int k0) {
#pragma unroll
        for (int it = 0; it < 2; it++) {
            int idx = it * 256 + tid;
            int r   = idx >> 2;
            int c8  = (idx & 3) * 8;
            gl_lds16(A + (rowBase + r) * KK + k0 + c8, &As[buf][idx * 8]);
            gl_lds16(W + (colBase + r) * KK + k0 + c8, &Bs[buf][idx * 8]);
        }
    };

    float4_ acc[4][4];
#pragma unroll
    for (int i = 0; i < 4; i++)
#pragma unroll
        for (int j = 0; j < 4; j++) acc[i][j] = float4_{0.f, 0.f, 0.f, 0.f};

    STAGE(0, 0);
    asm volatile("s_waitcnt vmcnt(0)" ::: "memory");
    __builtin_amdgcn_s_barrier();

    const int NT = KK / 32;
    for (int t = 0; t < NT; t++) {
        const int cur = t & 1;
        if (t + 1 < NT) STAGE(cur ^ 1, (t + 1) * 32);

        short8 af[4], bf[4];
#pragma unroll
        for (int mt = 0; mt < 4; mt++)
            af[mt] = *(const short8*)&As[cur][(wm*64 + mt*16 + l15) * 32 + quad*8];
#pragma unroll
        for (int nt = 0; nt < 4; nt++)
            bf[nt] = *(const short8*)&Bs[cur][(wn*64 + nt*16 + l15) * 32 + quad*8];
#pragma unroll
        for (int mt = 0; mt < 4; mt++)
#pragma unroll
            for (int nt = 0; nt < 4; nt++)
                acc[mt][nt] = __builtin_amdgcn_mfma_f32_16x16x32_bf16(
                    af[mt], bf[nt], acc[mt][nt], 0, 0, 0);

        if (t + 1 < NT) {
            asm volatile("s_waitcnt vmcnt(0)" ::: "memory");
            __builtin_amdgcn_s_barrier();
        }
    }

#pragma unroll
    for (int nt = 0; nt < 4; nt++) {
        const long col = colBase + wn*64 + nt*16 + l15;
        const float bv = bias[col];
#pragma unroll
        for (int mt = 0; mt < 4; mt++) {
            const long row0 = rowBase + wm*64 + mt*16 + quad*4;
#pragma unroll
            for (int i = 0; i < 4; i++)
                Cout[(row0 + i) * EE + col] = acc[mt][nt][i] + bv;
        }
    }
}

// ---------------------------------------------------------------------------
// Flash attention (causal). Q,K: [B*H, T, D] bf16; Vt: [B*H, D, T] bf16;
// AO: [B, T, E] bf16.  Q pre-scaled by 0.125*log2(e) -> softmax via exp2.
// (R10 form: pair-balanced 17-tile blocks, double-buffered K/V LDS with one
// barrier per tile, operand-swapped S^T = mfma(K,Q), scalar softmax state,
// P in registers.)
// ---------------------------------------------------------------------------
__global__ __launch_bounds__(512, 4) void flash_kernel(
    const ushort* __restrict__ Qh, const ushort* __restrict__ Kh,
    const ushort* __restrict__ Vt, ushort* __restrict__ AO)
{
    __shared__ __align__(16) ushort Ks[2][128*KSTR];   // [buf][key][d]  36.9 KB
    __shared__ __align__(16) ushort Vs[2][64*VSTR];    // [buf][d][key]  34.8 KB

    const int p   = blockIdx.x;                 // pair index 0..7
    const int bh  = blockIdx.y;                 // b*H + h
    const int tid = threadIdx.x;
    const int wave = tid >> 6, lane = tid & 63;
    const int l15 = lane & 15, quad = lane >> 4;

    const ushort* Qb = Qh + (long)bh * TT * DD;
    const ushort* Kb = Kh + (long)bh * TT * DD;
    const ushort* Vb = Vt + (long)bh * DD * TT;
    const int h = bh & (HH - 1);
    const int b = bh >> 4;

    // staging geometry (constant per thread)
    int kks[2], kss[2], dds[2], vss[2];
#pragma unroll
    for (int it = 0; it < 2; it++) {
        int c = it * 512 + tid;                 // 0..1023
        kks[it] = c >> 3; kss[it] = c & 7;      // K: key, 16B seg
        dds[it] = c >> 4; vss[it] = c & 15;     // V: d, 16B seg
    }

#pragma unroll
    for (int seg = 0; seg < 2; seg++) {
        const int qt  = (seg == 0) ? (15 - p) : p;   // heavy first
        const int nkt = qt + 1;

        // this segment's q-row (B-frag of swapped QK^T; also the output t)
        const int qrow = qt*128 + wave*16 + l15;
        short8 aq0 = *(const short8*)&Qb[(long)qrow * DD + quad*8];
        short8 aq1 = *(const short8*)&Qb[(long)qrow * DD + 32 + quad*8];

        float4_ o[4];
#pragma unroll
        for (int nt = 0; nt < 4; nt++) o[nt] = float4_{0.f, 0.f, 0.f, 0.f};
        float m_run = -INFINITY, l_run = 0.0f;

        // stage tile 0 -> buf 0
        short8 kreg[2], vreg[2];
#pragma unroll
        for (int it = 0; it < 2; it++) {
            kreg[it] = *(const short8*)&Kb[(long)kks[it] * DD + kss[it]*8];
            vreg[it] = *(const short8*)&Vb[(long)dds[it] * TT + vss[it]*8];
        }
        __syncthreads();   // all waves done reading every buffer (prev seg)
#pragma unroll
        for (int it = 0; it < 2; it++) {
            *(short8*)&Ks[0][kks[it]*KSTR + kss[it]*8] = kreg[it];
            *(short8*)&Vs[0][dds[it]*VSTR + vss[it]*8] = vreg[it];
        }
        __syncthreads();
        int cur = 0;

        for (int kt = 0; kt < nkt; kt++) {
            // prefetch next tile into regs (latency hides under compute)
            if (kt + 1 < nkt) {
                const long koff = (long)(kt+1) * 128;
#pragma unroll
                for (int it = 0; it < 2; it++) {
                    kreg[it] = *(const short8*)&Kb[(koff + kks[it]) * DD + kss[it]*8];
                    vreg[it] = *(const short8*)&Vb[(long)dds[it] * TT + koff + vss[it]*8];
                }
            }
            const ushort* ksb = &Ks[cur][0];
            const ushort* vsb = &Vs[cur][0];

            // S^T = mfma(K, Q): col = q = l15, row = key = quad*4 + i
            float4_ s[8];
            __builtin_amdgcn_s_setprio(1);
#pragma unroll
            for (int nt = 0; nt < 8; nt++) {
                short8 bk0 = *(const short8*)&ksb[(nt*16 + l15) * KSTR + quad*8];
                short8 bk1 = *(const short8*)&ksb[(nt*16 + l15) * KSTR + 32 + quad*8];
                float4_ acc = float4_{0.f, 0.f, 0.f, 0.f};
                acc = __builtin_amdgcn_mfma_f32_16x16x32_bf16(bk0, aq0, acc, 0,0,0);
                acc = __builtin_amdgcn_mfma_f32_16x16x32_bf16(bk1, aq1, acc, 0,0,0);
                s[nt] = acc;
            }
            __builtin_amdgcn_s_setprio(0);

            if (kt == nkt - 1) {   // only the diagonal tile crosses the mask
#pragma unroll
                for (int nt = 0; nt < 8; nt++) {
#pragma unroll
                    for (int i = 0; i < 4; i++) {
                        const int key = kt*128 + nt*16 + quad*4 + i;
                        if (key > qrow) s[nt][i] = -INFINITY;
                    }
                }
            }

            // row max: register tree over 32 keys + 2 cross-quad shfls
            float t8[8];
#pragma unroll
            for (int nt = 0; nt < 8; nt++)
                t8[nt] = fmaxf(fmaxf(s[nt][0], s[nt][1]), fmaxf(s[nt][2], s[nt][3]));
            float pm = fmaxf(fmaxf(fmaxf(t8[0], t8[1]), fmaxf(t8[2], t8[3])),
                             fmaxf(fmaxf(t8[4], t8[5]), fmaxf(t8[6], t8[7])));
            pm = fmaxf(pm, __shfl_xor(pm, 16));
            pm = fmaxf(pm, __shfl_xor(pm, 32));

            // T13 defer-max
            if (!__all(pm <= m_run + 8.0f)) {
                const float mnew = fmaxf(m_run, pm);
                const float alpha = exp2f(m_run - mnew);
                m_run = mnew;
                l_run *= alpha;
#pragma unroll
                for (int nt = 0; nt < 4; nt++)
#pragma unroll
                    for (int i = 0; i < 4; i++) o[nt][i] *= alpha;
            }

            // P = exp2(S - m): row sum + immediate bf16 pack
            float rs0 = 0.f, rs1 = 0.f, rs2 = 0.f, rs3 = 0.f;
            short8 pb[4];
#pragma unroll
            for (int c = 0; c < 4; c++) {
#pragma unroll
                for (int half = 0; half < 2; half++) {
                    const int nt = 2*c + half;
                    const float p0 = exp2f(s[nt][0] - m_run);
                    const float p1 = exp2f(s[nt][1] - m_run);
                    const float p2 = exp2f(s[nt][2] - m_run);
                    const float p3 = exp2f(s[nt][3] - m_run);
                    rs0 += p0; rs1 += p1; rs2 += p2; rs3 += p3;
                    pb[c][half*4 + 0] = (short)f2bf(p0);
                    pb[c][half*4 + 1] = (short)f2bf(p1);
                    pb[c][half*4 + 2] = (short)f2bf(p2);
                    pb[c][half*4 + 3] = (short)f2bf(p3);
                }
            }
            float rs = (rs0 + rs1) + (rs2 + rs3);
            rs += __shfl_xor(rs, 16);
            rs += __shfl_xor(rs, 32);
            l_run += rs;

            // O^T += V^T @ P^T, P from registers.
            __builtin_amdgcn_s_setprio(1);
#pragma unroll
            for (int c = 0; c < 4; c++) {
                const short8 bp = pb[c];
#pragma unroll
                for (int nt = 0; nt < 4; nt++) {
                    const ushort* vrow = &vsb[(nt*16 + l15) * VSTR];
                    short4_ lo = *(const short4_*)&vrow[(2*c    )*16 + quad*4];
                    short4_ hi = *(const short4_*)&vrow[(2*c + 1)*16 + quad*4];
                    short8 av;
                    av[0]=lo[0]; av[1]=lo[1]; av[2]=lo[2]; av[3]=lo[3];
                    av[4]=hi[0]; av[5]=hi[1]; av[6]=hi[2]; av[7]=hi[3];
                    o[nt] = __builtin_amdgcn_mfma_f32_16x16x32_bf16(av, bp, o[nt], 0,0,0);
                }
            }
            __builtin_amdgcn_s_setprio(0);

            // publish next tile into the other buffer; single barrier per tile
            if (kt + 1 < nkt) {
#pragma unroll
                for (int it = 0; it < 2; it++) {
                    *(short8*)&Ks[cur^1][kks[it]*KSTR + kss[it]*8] = kreg[it];
                    *(short8*)&Vs[cur^1][dds[it]*VSTR + vss[it]*8] = vreg[it];
                }
                __syncthreads();
                cur ^= 1;
            }
        }

        // epilogue: AO[b, t=qrow, h*64 + d] = o / l
        const float inv = 1.0f / l_run;
        const long rowOff = ((long)(b*TT + qrow)) * EE + h*64;
#pragma unroll
        for (int nt = 0; nt < 4; nt++) {
            ushort4_ pk;
#pragma unroll
            for (int i = 0; i < 4; i++) pk[i] = f2bf(o[nt][i] * inv);
            *(ushort4_*)&AO[rowOff + nt*16 + quad*4] = pk;
        }
    }
}

// ---------------------------------------------------------------------------
extern "C" void kernel_launch(void* const* d_in, const int* in_sizes, int n_in,
                              void* d_out, int out_size, void* d_ws, size_t ws_size,
                              hipStream_t stream)
{
    const float* query  = (const float*)d_in[0];
    const float* key_in = (const float*)d_in[1];
    const float* value  = (const float*)d_in[2];
    // d_in[3] = mask (int32 tril) — causal is hard-coded in flash_kernel
    const float* Wq = (const float*)d_in[4];
    const float* bq = (const float*)d_in[5];
    const float* Wk = (const float*)d_in[6];
    const float* bk = (const float*)d_in[7];
    const float* Wv = (const float*)d_in[8];
    const float* bv = (const float*)d_in[9];
    const float* Wo = (const float*)d_in[10];
    const float* bo = (const float*)d_in[11];

    ushort* ws = (ushort*)d_ws;
    const size_t NIN = (size_t)MM * KK;        // 8,388,608 elems
    const size_t NW  = (size_t)EE * KK;        // 1,048,576 elems (weights)
    ushort* Wqc = ws;                          // 2 MB each
    ushort* Wkc = Wqc + NW;
    ushort* Wvc = Wkc + NW;
    ushort* Woc = Wvc + NW;
    ushort* Qh  = Woc + NW;                    // 16 MB  [bh][t][d], pre-scaled
    ushort* Kh  = Qh + NIN;                    // 16 MB  [bh][t][d]
    ushort* Vth = Kh + NIN;                    // 16 MB  [bh][d][t]
    ushort* AO  = Vth + NIN;                   // 16 MB  [b][t][e]  (total 72 MB)

    const dim3 cvtW_grid(NW/1024, 4);

    // weights -> bf16 (one batched launch)
    cvt_kernel<<<cvtW_grid, 256, 0, stream>>>(Wq, Wqc, (int)NW, Wk, Wkc, (int)NW,
                                              Wv, Wvc, (int)NW, Wo, Woc, (int)NW);

    // Q/K/V projections merged, 1D grid with XCD-chunked swizzle
    gemm_qkv<<<dim3(3 * (EE/128) * (MM/128)), 256, 0, stream>>>(
        query, key_in, value, Wqc, Wkc, Wvc, bq, bk, bv, Qh, Kh, Vth,
        0.125f * LOG2E);

    // pair-balanced causal flash: 8 pairs x 64 heads, 17 tiles per block
    flash_kernel<<<dim3(8, BH), 512, 0, stream>>>(Qh, Kh, Vth, AO);

    gemm_out<<<dim3((EE/128) * (MM/128)), 256, 0, stream>>>(AO, Woc, bo, (float*)d_out);
}